// Round 3
// baseline (601.234 us; speedup 1.0000x reference)
//
#include <hip/hip_runtime.h>

typedef unsigned short u16;
typedef float    f32x4  __attribute__((ext_vector_type(4)));
typedef __bf16   bf16x8 __attribute__((ext_vector_type(8)));
typedef u16      u16x4  __attribute__((ext_vector_type(4)));
typedef u16      u16x8  __attribute__((ext_vector_type(8)));

#define NB   8
#define NS   2048
#define ND   1024

__device__ __forceinline__ u16 f2bf(float x) {
    union { float f; unsigned u; } v; v.f = x;
    unsigned r = v.u + 0x7fffu + ((v.u >> 16) & 1u);
    return (u16)(r >> 16);
}
__device__ __forceinline__ float bf2f(u16 x) {
    union { unsigned u; float f; } v; v.u = ((unsigned)x) << 16;
    return v.f;
}

// ---------------------------------------------------------------- cvt f32->bf16
__global__ __launch_bounds__(256) void cvt_f32_bf16(const float* __restrict__ in,
                                                    u16* __restrict__ out, int n4) {
    int i = blockIdx.x * 256 + threadIdx.x;
    if (i >= n4) return;
    f32x4 v = ((const f32x4*)in)[i];
    u16x4 o;
    o[0] = f2bf(v[0]); o[1] = f2bf(v[1]); o[2] = f2bf(v[2]); o[3] = f2bf(v[3]);
    ((u16x4*)out)[i] = o;
}

// ---------------------------------------------------------------- GEMM  C = A * B^T
// A: [M x K] row-major bf16 (u16), B: [N x K] row-major bf16 (B^T form)
// 128x128 tile, BK=32, 256 threads (4 waves, each 64x64), mfma 16x16x32 bf16.
// BIAS: 0 none, 1 += bias[col], 2 += bias[row].  OUT_BF16: 1 -> u16 out, 0 -> f32 out.
template<int OUT_BF16, int BIAS>
__global__ __launch_bounds__(256, 2)
void gemm_bt_kernel(const u16* __restrict__ A, long long sA, int lda,
                    const u16* __restrict__ B, long long sB, int ldb,
                    void* __restrict__ Cv, long long sC, int ldc,
                    const float* __restrict__ bias, int K)
{
    __shared__ alignas(16) u16 ldsA[128 * 32];
    __shared__ alignas(16) u16 ldsB[128 * 32];
    const int z = blockIdx.z;
    A += sA * z;
    B += sB * z;
    const int t = threadIdx.x;
    const int w = t >> 6, l = t & 63;
    const int row0 = blockIdx.y * 128, col0 = blockIdx.x * 128;
    const int wr = (w >> 1) << 6, wc = (w & 1) << 6;

    f32x4 acc[4][4] = {};
    const int lr = l & 15, lk = (l >> 4) << 3;

    for (int kt = 0; kt < K; kt += 32) {
#pragma unroll
        for (int i = 0; i < 2; ++i) {
            const int c  = (i << 8) + t;          // chunk id 0..511 (16B chunks)
            const int r  = c >> 2;                // tile row 0..127
            const int k8 = (c & 3) << 3;          // k offset 0,8,16,24
            const u16* ga = A + (long long)(row0 + r) * lda + (kt + k8);
            const u16* gb = B + (long long)(col0 + r) * ldb + (kt + k8);
            // wave-uniform LDS base; HW scatters lane i at +16*i
            u16* la = &ldsA[((i << 8) + (w << 6)) << 3];
            u16* lb = &ldsB[((i << 8) + (w << 6)) << 3];
            __builtin_amdgcn_global_load_lds((__attribute__((address_space(1))) void*)ga,
                                             (__attribute__((address_space(3))) void*)la, 16, 0, 0);
            __builtin_amdgcn_global_load_lds((__attribute__((address_space(1))) void*)gb,
                                             (__attribute__((address_space(3))) void*)lb, 16, 0, 0);
        }
        __syncthreads();

        bf16x8 af[4], bfr[4];
#pragma unroll
        for (int m = 0; m < 4; ++m)
            af[m] = *(const bf16x8*)&ldsA[(wr + (m << 4) + lr) * 32 + lk];
#pragma unroll
        for (int n = 0; n < 4; ++n)
            bfr[n] = *(const bf16x8*)&ldsB[(wc + (n << 4) + lr) * 32 + lk];
#pragma unroll
        for (int m = 0; m < 4; ++m)
#pragma unroll
            for (int n = 0; n < 4; ++n)
                acc[m][n] = __builtin_amdgcn_mfma_f32_16x16x32_bf16(af[m], bfr[n], acc[m][n], 0, 0, 0);
        __syncthreads();
    }

    // epilogue: D row = (l>>4)*4 + j, col = l&15   [m89-verified layout]
    const int fr = l & 15, fq = (l >> 4) << 2;
    u16*   Cb = (u16*)Cv + sC * z;
    float* Cf = (float*)Cv + sC * z;
#pragma unroll
    for (int m = 0; m < 4; ++m) {
#pragma unroll
        for (int n = 0; n < 4; ++n) {
#pragma unroll
            for (int j = 0; j < 4; ++j) {
                const int r  = row0 + wr + (m << 4) + fq + j;
                const int cc = col0 + wc + (n << 4) + fr;
                float vv = acc[m][n][j];
                if (BIAS == 1) vv += bias[cc];
                else if (BIAS == 2) vv += bias[r];
                if (OUT_BF16) Cb[(long long)r * ldc + cc] = f2bf(vv);
                else          Cf[(long long)r * ldc + cc] = vv;
            }
        }
    }
}

// ---------------------------------------------------------------- row softmax (bf16 in/out, in place)
// One block per row of 2048 bf16 scores. scale2 = (1/sqrt(DK)) * log2(e).
__global__ __launch_bounds__(256, 4)
void softmax_kernel(u16* __restrict__ sc, float scale2) {
    u16* row = sc + (long long)blockIdx.x * NS;
    const int t = threadIdx.x;
    u16x8 a = ((const u16x8*)row)[t];
    float x[8];
#pragma unroll
    for (int j = 0; j < 8; ++j) x[j] = bf2f(a[j]);
    float m = x[0];
#pragma unroll
    for (int j = 1; j < 8; ++j) m = fmaxf(m, x[j]);
#pragma unroll
    for (int off = 1; off < 64; off <<= 1) m = fmaxf(m, __shfl_xor(m, off));
    __shared__ float red[2][4];
    const int w = t >> 6;
    if ((t & 63) == 0) red[0][w] = m;
    __syncthreads();
    m = fmaxf(fmaxf(red[0][0], red[0][1]), fmaxf(red[0][2], red[0][3]));
    float e[8], s = 0.f;
#pragma unroll
    for (int j = 0; j < 8; ++j) { e[j] = exp2f((x[j] - m) * scale2); s += e[j]; }
#pragma unroll
    for (int off = 1; off < 64; off <<= 1) s += __shfl_xor(s, off);
    if ((t & 63) == 0) red[1][w] = s;
    __syncthreads();
    s = red[1][0] + red[1][1] + red[1][2] + red[1][3];
    const float inv = 1.0f / s;
    u16x8 o;
#pragma unroll
    for (int j = 0; j < 8; ++j) o[j] = f2bf(e[j] * inv);
    ((u16x8*)row)[t] = o;
}

// ---------------------------------------------------------------- launch
extern "C" void kernel_launch(void* const* d_in, const int* in_sizes, int n_in,
                              void* d_out, int out_size, void* d_ws, size_t ws_size,
                              hipStream_t stream) {
    const float* q  = (const float*)d_in[0];
    const float* k  = (const float*)d_in[1];
    const float* v  = (const float*)d_in[2];
    const float* wq = (const float*)d_in[3];
    const float* bq = (const float*)d_in[4];
    const float* wk = (const float*)d_in[5];
    const float* bk = (const float*)d_in[6];
    const float* wv = (const float*)d_in[7];
    const float* bv = (const float*)d_in[8];
    float* out = (float*)d_out;

    char* ws = (char*)d_ws;
    const long long NIN = (long long)NB * NS * ND;     // 16,777,216 elems
    const long long NW  = (long long)ND * ND;          // 1,048,576 elems
    const long long NSC = (long long)NB * NS * NS;     // 33,554,432 elems

    // Workspace layout (160 MiB total):
    //  [0, 67.1MB)   SCB  bf16 scores  -- X (33.5MB) and W (2MB) alias here early
    //  [67.1, 100.7) QB
    //  [100.7,134.2) KB
    //  [134.2,167.8) VT  (V^T: [B][D][S])
    u16* SCB = (u16*)ws;
    u16* X   = (u16*)ws;                    // aliases SCB[0 : NIN)
    u16* W   = X + NIN;                     // aliases SCB[NIN : NIN+NW)
    u16* QB  = SCB + NSC;
    u16* KB  = QB + NIN;
    u16* VT  = KB + NIN;
    (void)ws_size; (void)in_sizes; (void)n_in; (void)out_size;

    // 1) Q projection: cvt q->X, wq->W; QB = X * W^T + bq  (M=16384,N=1024,K=1024)
    cvt_f32_bf16<<<16384, 256, 0, stream>>>(q,  X, (int)(NIN / 4));
    cvt_f32_bf16<<<1024,  256, 0, stream>>>(wq, W, (int)(NW / 4));
    gemm_bt_kernel<1, 1><<<dim3(8, 128, 1), 256, 0, stream>>>(
        X, 0, ND, W, 0, ND, QB, 0, ND, bq, ND);

    // 2) K projection
    cvt_f32_bf16<<<16384, 256, 0, stream>>>(k,  X, (int)(NIN / 4));
    cvt_f32_bf16<<<1024,  256, 0, stream>>>(wk, W, (int)(NW / 4));
    gemm_bt_kernel<1, 1><<<dim3(8, 128, 1), 256, 0, stream>>>(
        X, 0, ND, W, 0, ND, KB, 0, ND, bk, ND);

    // 3) V^T projection: VT[b][v][s] = sum_d Wv[v,d]*Xv[b,s,d] + bv[v]
    //    per batch M=1024(v), N=2048(s), bias along M(row)
    cvt_f32_bf16<<<16384, 256, 0, stream>>>(v,  X, (int)(NIN / 4));
    cvt_f32_bf16<<<1024,  256, 0, stream>>>(wv, W, (int)(NW / 4));
    gemm_bt_kernel<1, 2><<<dim3(16, 8, NB), 256, 0, stream>>>(
        W, 0, ND, X, (long long)NS * ND, ND, VT, (long long)ND * NS, NS, bv, ND);

    // 4) scores[b] = Q[b] * K[b]^T  (bf16 out; X/W now dead, SCB overwrites them)
    gemm_bt_kernel<1, 0><<<dim3(16, 16, NB), 256, 0, stream>>>(
        QB, (long long)NS * ND, ND, KB, (long long)NS * ND, ND,
        SCB, (long long)NS * NS, NS, nullptr, ND);

    // 5) softmax rows, scale folded into exp2
    const float scale2 = (1.0f / 32.0f) * 1.44269504088896f; // 1/sqrt(1024)*log2(e)
    softmax_kernel<<<NB * NS, 256, 0, stream>>>(SCB, scale2);

    // 6) out[b] = attn[b] * V[b] : A = bf16 attn [S x S], B^T = V^T[b], f32 out
    gemm_bt_kernel<0, 0><<<dim3(8, 16, NB), 256, 0, stream>>>(
        SCB, (long long)NS * NS, NS,
        VT, (long long)ND * NS, NS,
        out, (long long)NS * ND, ND, nullptr, NS);
}

// Round 5
// 506.800 us; speedup vs baseline: 1.1863x; 1.1863x over previous
//
#include <hip/hip_runtime.h>

typedef unsigned short u16;
typedef float    f32x4  __attribute__((ext_vector_type(4)));
typedef __bf16   bf16x8 __attribute__((ext_vector_type(8)));
typedef u16      u16x4  __attribute__((ext_vector_type(4)));
typedef u16      u16x8  __attribute__((ext_vector_type(8)));

#define NB   8
#define NS   2048
#define ND   1024

__device__ __forceinline__ u16 f2bf(float x) {
    union { float f; unsigned u; } v; v.f = x;
    unsigned r = v.u + 0x7fffu + ((v.u >> 16) & 1u);
    return (u16)(r >> 16);
}
__device__ __forceinline__ float bf2f(u16 x) {
    union { unsigned u; float f; } v; v.u = ((unsigned)x) << 16;
    return v.f;
}

// ---------------------------------------------------------------- cvt f32->bf16
__global__ __launch_bounds__(256) void cvt_f32_bf16(const float* __restrict__ in,
                                                    u16* __restrict__ out, int n4) {
    int i = blockIdx.x * 256 + threadIdx.x;
    if (i >= n4) return;
    f32x4 v = ((const f32x4*)in)[i];
    u16x4 o;
    o[0] = f2bf(v[0]); o[1] = f2bf(v[1]); o[2] = f2bf(v[2]); o[3] = f2bf(v[3]);
    ((u16x4*)out)[i] = o;
}

// ---------------------------------------------------------------- GEMM  C = A * B^T
// 256x256 tile, BK=32, 512 threads = 8 waves (2M x 4N), per-wave 128x64 output.
// 3 LDS buffers (96KB), 2-tile-ahead prefetch with counted vmcnt (T3/T4),
// T2 XOR-swizzled LDS (swizzle on global src + ds_read addr; linear gll dest),
// T5 setprio around MFMA cluster, T1 bijective XCD block swizzle.
// A: [M x K] row-major bf16, B: [N x K] row-major bf16 (B^T layout).
// M, N multiples of 256; K multiple of 32 and >= 96.
// BIAS: 0 none, 1 += bias[col], 2 += bias[row].  OUT_BF16: 1 u16 out, 0 f32 out.
template<int OUT_BF16, int BIAS>
__global__ __launch_bounds__(512, 2)
void gemm256_kernel(const u16* __restrict__ A, long long sA, int lda,
                    const u16* __restrict__ B, long long sB, int ldb,
                    void* __restrict__ Cv, long long sC, int ldc,
                    const float* __restrict__ bias, int K)
{
    __shared__ alignas(16) u16 lds[49152];   // 3 x (16KB A + 16KB B)

    // T1: bijective XCD swizzle (all grids here have nwg % 8 == 0)
    const int gx = gridDim.x, gy = gridDim.y;
    const int nwg = gx * gy * (int)gridDim.z;
    const int lin = blockIdx.x + gx * (blockIdx.y + gy * blockIdx.z);
    const int chunk = nwg >> 3;
    const int swz = (lin & 7) * chunk + (lin >> 3);
    const int bx = swz % gx;
    const int tq = swz / gx;
    const int by = tq % gy;
    const int bz = tq / gy;

    A += sA * bz;
    B += sB * bz;

    const int row0 = by << 8, col0 = bx << 8;
    const int t = threadIdx.x;
    const int w = t >> 6, l = t & 63;
    const int wm = w >> 2, wn = w & 3;

    // ---- staging (global_load_lds, width 16): LDS slot s = r*4 + (j0 ^ ((r>>1)&3))
    // stage instr i in {0,1}: slots s = i*512 + w*64 + l  ->  r = i*128 + w*16 + (l>>2)
    // swizzle folded into the per-lane GLOBAL source (rule 21); LDS dest linear.
    const int j0e = ((l & 3) ^ ((l >> 3) & 3)) << 3;             // source k-offset (elems)
    const u16* gA0 = A + (long long)(row0 + (w << 4) + (l >> 2)) * lda + j0e;
    const u16* gA1 = gA0 + ((long long)lda << 7);                // +128 rows
    const u16* gB0 = B + (long long)(col0 + (w << 4) + (l >> 2)) * ldb + j0e;
    const u16* gB1 = gB0 + ((long long)ldb << 7);
    const unsigned dA0 = (unsigned)(w << 10);                    // wave-uniform byte base

    auto STAGE = [&](int buf, int kt) {
        const unsigned bo = (unsigned)buf * 32768u;
        __builtin_amdgcn_global_load_lds((__attribute__((address_space(1))) void*)(gA0 + kt),
            (__attribute__((address_space(3))) void*)((char*)lds + bo + dA0),          16, 0, 0);
        __builtin_amdgcn_global_load_lds((__attribute__((address_space(1))) void*)(gA1 + kt),
            (__attribute__((address_space(3))) void*)((char*)lds + bo + dA0 + 8192),   16, 0, 0);
        __builtin_amdgcn_global_load_lds((__attribute__((address_space(1))) void*)(gB0 + kt),
            (__attribute__((address_space(3))) void*)((char*)lds + bo + 16384 + dA0),  16, 0, 0);
        __builtin_amdgcn_global_load_lds((__attribute__((address_space(1))) void*)(gB1 + kt),
            (__attribute__((address_space(3))) void*)((char*)lds + bo + 16384 + dA0 + 8192), 16, 0, 0);
    };

    // ---- ds_read addresses (same involution; (r>>1)&3 == (lr>>1)&3 since frag base % 16 == 0)
    const int lr  = l & 15;
    const int jsw = ((l >> 4) ^ ((lr >> 1) & 3)) << 4;           // swizzled 16B slot (bytes)
    const int aA  = ((wm << 7) + lr) * 64 + jsw;                 // frag mf: +mf*1024
    const int aB  = 16384 + ((wn << 6) + lr) * 64 + jsw;         // frag nf: +nf*1024

    f32x4 acc[8][4] = {};
    const int NT = K >> 5;

    STAGE(0, 0);
    STAGE(1, 32);

    for (int tt = 0; tt < NT; ++tt) {
        if (tt + 2 < NT) {
            STAGE((tt + 2) % 3, (tt + 2) << 5);
            asm volatile("s_waitcnt vmcnt(8)" ::: "memory");     // tile tt landed; 2 in flight
        } else if (tt + 1 < NT) {
            asm volatile("s_waitcnt vmcnt(4)" ::: "memory");
        } else {
            asm volatile("s_waitcnt vmcnt(0)" ::: "memory");
        }
        __builtin_amdgcn_s_barrier();                            // tile tt visible to all waves

        const char* bufp = (const char*)lds + (tt % 3) * 32768;
        bf16x8 af[8], bfv[4];
#pragma unroll
        for (int mf = 0; mf < 8; ++mf) af[mf]  = *(const bf16x8*)(bufp + aA + mf * 1024);
#pragma unroll
        for (int nf = 0; nf < 4; ++nf) bfv[nf] = *(const bf16x8*)(bufp + aB + nf * 1024);

        asm volatile("s_waitcnt lgkmcnt(0)" ::: "memory");       // reads serviced...
        __builtin_amdgcn_s_barrier();                            // ...before buffer reuse

        __builtin_amdgcn_s_setprio(1);
#pragma unroll
        for (int mf = 0; mf < 8; ++mf)
#pragma unroll
            for (int nf = 0; nf < 4; ++nf)
                acc[mf][nf] = __builtin_amdgcn_mfma_f32_16x16x32_bf16(af[mf], bfv[nf], acc[mf][nf], 0, 0, 0);
        __builtin_amdgcn_s_setprio(0);
    }

    // ---- epilogue: C row = (l>>4)*4 + j, col = l&15 within each 16x16 frag [m89]
    const int fr = l & 15, fq = (l >> 4) << 2;
    u16*   Cb = (u16*)Cv + sC * bz;
    float* Cf = (float*)Cv + sC * bz;
#pragma unroll
    for (int mf = 0; mf < 8; ++mf) {
        const int r = row0 + (wm << 7) + (mf << 4) + fq;
#pragma unroll
        for (int nf = 0; nf < 4; ++nf) {
            const int c = col0 + (wn << 6) + (nf << 4) + fr;
#pragma unroll
            for (int j = 0; j < 4; ++j) {
                float vv = acc[mf][nf][j];
                if (BIAS == 1) vv += bias[c];
                else if (BIAS == 2) vv += bias[r + j];
                if (OUT_BF16) Cb[(long long)(r + j) * ldc + c] = f2bf(vv);
                else          Cf[(long long)(r + j) * ldc + c] = vv;
            }
        }
    }
}

// ---------------------------------------------------------------- row softmax (bf16 in/out, in place)
__global__ __launch_bounds__(256, 4)
void softmax_kernel(u16* __restrict__ sc, float scale2) {
    u16* row = sc + (long long)blockIdx.x * NS;
    const int t = threadIdx.x;
    u16x8 a = ((const u16x8*)row)[t];
    float x[8];
#pragma unroll
    for (int j = 0; j < 8; ++j) x[j] = bf2f(a[j]);
    float m = x[0];
#pragma unroll
    for (int j = 1; j < 8; ++j) m = fmaxf(m, x[j]);
#pragma unroll
    for (int off = 1; off < 64; off <<= 1) m = fmaxf(m, __shfl_xor(m, off));
    __shared__ float red[2][4];
    const int w = t >> 6;
    if ((t & 63) == 0) red[0][w] = m;
    __syncthreads();
    m = fmaxf(fmaxf(red[0][0], red[0][1]), fmaxf(red[0][2], red[0][3]));
    float e[8], s = 0.f;
#pragma unroll
    for (int j = 0; j < 8; ++j) { e[j] = exp2f((x[j] - m) * scale2); s += e[j]; }
#pragma unroll
    for (int off = 1; off < 64; off <<= 1) s += __shfl_xor(s, off);
    if ((t & 63) == 0) red[1][w] = s;
    __syncthreads();
    s = red[1][0] + red[1][1] + red[1][2] + red[1][3];
    const float inv = 1.0f / s;
    u16x8 o;
#pragma unroll
    for (int j = 0; j < 8; ++j) o[j] = f2bf(e[j] * inv);
    ((u16x8*)row)[t] = o;
}

// ---------------------------------------------------------------- launch
extern "C" void kernel_launch(void* const* d_in, const int* in_sizes, int n_in,
                              void* d_out, int out_size, void* d_ws, size_t ws_size,
                              hipStream_t stream) {
    const float* q  = (const float*)d_in[0];
    const float* k  = (const float*)d_in[1];
    const float* v  = (const float*)d_in[2];
    const float* wq = (const float*)d_in[3];
    const float* bq = (const float*)d_in[4];
    const float* wk = (const float*)d_in[5];
    const float* bk = (const float*)d_in[6];
    const float* wv = (const float*)d_in[7];
    const float* bv = (const float*)d_in[8];
    float* out = (float*)d_out;

    char* ws = (char*)d_ws;
    const long long NIN = (long long)NB * NS * ND;     // 16,777,216 elems
    const long long NW  = (long long)ND * ND;          // 1,048,576 elems
    const long long NSC = (long long)NB * NS * NS;     // 33,554,432 elems

    // Workspace (160 MiB): [SCB bf16 scores 67MB | QB 33.5 | KB 33.5 | VT 33.5]
    // X (33.5MB) and W (2MB) alias the SCB region (dead before scores are written).
    u16* SCB = (u16*)ws;
    u16* X   = (u16*)ws;
    u16* W   = X + NIN;
    u16* QB  = SCB + NSC;
    u16* KB  = QB + NIN;
    u16* VT  = KB + NIN;
    (void)ws_size; (void)in_sizes; (void)n_in; (void)out_size;

    // 1) Q projection
    cvt_f32_bf16<<<16384, 256, 0, stream>>>(q,  X, (int)(NIN / 4));
    cvt_f32_bf16<<<1024,  256, 0, stream>>>(wq, W, (int)(NW / 4));
    gemm256_kernel<1, 1><<<dim3(4, 64, 1), 512, 0, stream>>>(
        X, 0, ND, W, 0, ND, QB, 0, ND, bq, ND);

    // 2) K projection
    cvt_f32_bf16<<<16384, 256, 0, stream>>>(k,  X, (int)(NIN / 4));
    cvt_f32_bf16<<<1024,  256, 0, stream>>>(wk, W, (int)(NW / 4));
    gemm256_kernel<1, 1><<<dim3(4, 64, 1), 512, 0, stream>>>(
        X, 0, ND, W, 0, ND, KB, 0, ND, bk, ND);

    // 3) V^T projection: VT[b][v][s] = sum_d Wv[v,d]*Xv[b,s,d] + bv[v]
    cvt_f32_bf16<<<16384, 256, 0, stream>>>(v,  X, (int)(NIN / 4));
    cvt_f32_bf16<<<1024,  256, 0, stream>>>(wv, W, (int)(NW / 4));
    gemm256_kernel<1, 2><<<dim3(8, 4, NB), 512, 0, stream>>>(
        W, 0, ND, X, (long long)NS * ND, ND, VT, (long long)ND * NS, NS, bv, ND);

    // 4) scores[b] = Q[b] * K[b]^T  (bf16 out; X/W dead, SCB overwrites them)
    gemm256_kernel<1, 0><<<dim3(8, 8, NB), 512, 0, stream>>>(
        QB, (long long)NS * ND, ND, KB, (long long)NS * ND, ND,
        SCB, (long long)NS * NS, NS, nullptr, ND);

    // 5) softmax rows (scale folded into exp2)
    const float scale2 = (1.0f / 32.0f) * 1.44269504088896f; // 1/sqrt(1024)*log2(e)
    softmax_kernel<<<NB * NS, 256, 0, stream>>>(SCB, scale2);

    // 6) out[b] = attn[b] * V[b] : A = bf16 attn, B^T = V^T[b], f32 out
    gemm256_kernel<0, 0><<<dim3(4, 8, NB), 512, 0, stream>>>(
        SCB, (long long)NS * NS, NS,
        VT, (long long)ND * NS, NS,
        out, (long long)NS * ND, ND, nullptr, NS);
}

// Round 6
// 493.207 us; speedup vs baseline: 1.2190x; 1.0276x over previous
//
#include <hip/hip_runtime.h>

typedef unsigned short u16;
typedef float    f32x4  __attribute__((ext_vector_type(4)));
typedef __bf16   bf16x8 __attribute__((ext_vector_type(8)));
typedef u16      u16x4  __attribute__((ext_vector_type(4)));
typedef u16      u16x8  __attribute__((ext_vector_type(8)));

#define NB   8
#define NS   2048
#define ND   1024

__device__ __forceinline__ u16 f2bf(float x) {
    union { float f; unsigned u; } v; v.f = x;
    unsigned r = v.u + 0x7fffu + ((v.u >> 16) & 1u);
    return (u16)(r >> 16);
}
__device__ __forceinline__ float bf2f(u16 x) {
    union { unsigned u; float f; } v; v.u = ((unsigned)x) << 16;
    return v.f;
}

// ---------------------------------------------------------------- cvt f32->bf16
__global__ __launch_bounds__(256) void cvt_f32_bf16(const float* __restrict__ in,
                                                    u16* __restrict__ out, int n4) {
    int i = blockIdx.x * 256 + threadIdx.x;
    if (i >= n4) return;
    f32x4 v = ((const f32x4*)in)[i];
    u16x4 o;
    o[0] = f2bf(v[0]); o[1] = f2bf(v[1]); o[2] = f2bf(v[2]); o[3] = f2bf(v[3]);
    ((u16x4*)out)[i] = o;
}

// ---------------------------------------------------------------- GEMM  C = A * B^T
// 256x256 tile, BK=64, 512 thr (8 waves, 2Mx4N), 4-phase interleave per K-tile
// (T3+T4 counted vmcnt), 2x64KB LDS double buffer, T2 XOR swizzle, T5 setprio,
// T1 bijective XCD swizzle. A:[MxK], B:[NxK] row-major bf16. K % 64 == 0.
#define GLL(src, dst) __builtin_amdgcn_global_load_lds( \
    (const __attribute__((address_space(1))) void*)(src), \
    (__attribute__((address_space(3))) void*)((char*)lds + (dst)), 16, 0, 0)
#define MFMA16(a, b, c) __builtin_amdgcn_mfma_f32_16x16x32_bf16(a, b, c, 0, 0, 0)

template<int OUT_BF16, int BIAS>
__global__ __launch_bounds__(512, 2)
void gemm256_kernel(const u16* __restrict__ A, long long sA, int lda,
                    const u16* __restrict__ B, long long sB, int ldb,
                    void* __restrict__ Cv, long long sC, int ldc,
                    const float* __restrict__ bias, int K)
{
    __shared__ alignas(16) u16 lds[65536];   // 128 KiB: 2 bufs x (A 32K | B 32K)

    // T1: bijective XCD swizzle (all grids have nwg % 8 == 0)
    const int gx = gridDim.x, gy = gridDim.y;
    const int nwg = gx * gy * (int)gridDim.z;
    const int lin = blockIdx.x + gx * (blockIdx.y + gy * blockIdx.z);
    const int chunk = nwg >> 3;
    const int swz = (lin & 7) * chunk + (lin >> 3);
    const int bx = swz % gx;
    const int tq = swz / gx;
    const int by = tq % gy;
    const int bz = tq / gy;

    A += sA * bz;
    B += sB * bz;

    const int row0 = by << 8, col0 = bx << 8;
    const int t = threadIdx.x;
    const int w = t >> 6, l = t & 63;
    const int wm = w >> 2, wn = w & 3;
    const int lr = l & 15, hi = l >> 4;

    // ---- staging: LDS dest linear (t*16 within 8KB chunk); swizzle on global src.
    // Within a 16KB half: row rh = i*64 + (t>>3), slot = t&7 holds global col
    // ((slot ^ (rh&7)) * 8). Read side applies the same involution.
    const int tr = t >> 3, ts = t & 7;
    const int scol = ((ts ^ (tr & 7)) << 3);
    const u16* gA = A + (long long)(row0 + tr) * lda + scol;
    const u16* gB = B + (long long)(col0 + tr) * ldb + scol;
    const unsigned sdst = (unsigned)(t << 4);

    auto STAGE_A = [&](unsigned bufb, int kt, int h) {     // A half h: rows h*128..+127
        const u16* g = gA + (long long)(h << 7) * lda + kt;
        const unsigned d = bufb + (unsigned)(h << 14) + sdst;
        GLL(g, d);
        GLL(g + ((long long)lda << 6), d + 8192u);
    };
    auto STAGE_B = [&](unsigned bufb, int kt, int h) {
        const u16* g = gB + (long long)(h << 7) * ldb + kt;
        const unsigned d = bufb + 32768u + (unsigned)(h << 14) + sdst;
        GLL(g, d);
        GLL(g + ((long long)ldb << 6), d + 8192u);
    };

    // ---- read bases: frag(row = wm*128 + mf*16 + lr, k-slot = ks*4 + hi)
    const unsigned sw0    = (unsigned)((hi ^ (lr & 7)) << 4);  // ks=0 slot byte; ks=1: ^64
    const unsigned aAbase = (unsigned)(wm * 16384 + lr * 128);
    const unsigned aBbase = 32768u + (unsigned)((wn >> 1) * 16384 + ((wn & 1) * 64 + lr) * 128);

    f32x4 acc[8][4] = {};
    bf16x8 av[4][2], bv[4][2];
    const int NT = K >> 6;

    STAGE_A(0, 0, 0); STAGE_A(0, 0, 1); STAGE_B(0, 0, 0); STAGE_B(0, 0, 1);

    for (int tt = 0; tt < NT; ++tt) {
        const unsigned cb = (unsigned)((tt & 1) << 16);
        const unsigned nb = (unsigned)((~tt & 1) << 16);
        const int kt1 = (tt + 1) << 6;
        const bool st = (tt + 1 < NT);

        asm volatile("s_waitcnt vmcnt(0)" ::: "memory");   // tile tt landed (aged >=3 phases)
        __builtin_amdgcn_s_barrier();

        // ---- phase 0: read A-low(8) + B-low(4); stage next-tile A halves
#pragma unroll
        for (int m = 0; m < 4; ++m) {
            av[m][0] = *(const bf16x8*)((const char*)lds + cb + aAbase + m * 2048 + sw0);
            av[m][1] = *(const bf16x8*)((const char*)lds + cb + aAbase + m * 2048 + (sw0 ^ 64u));
        }
#pragma unroll
        for (int n = 0; n < 2; ++n) {
            bv[n][0] = *(const bf16x8*)((const char*)lds + cb + aBbase + n * 2048 + sw0);
            bv[n][1] = *(const bf16x8*)((const char*)lds + cb + aBbase + n * 2048 + (sw0 ^ 64u));
        }
        if (st) { STAGE_A(nb, kt1, 0); STAGE_A(nb, kt1, 1); }
        __builtin_amdgcn_s_barrier();
        asm volatile("s_waitcnt lgkmcnt(0)" ::: "memory");
        __builtin_amdgcn_sched_barrier(0);
        __builtin_amdgcn_s_setprio(1);
#pragma unroll
        for (int m = 0; m < 4; ++m)
#pragma unroll
            for (int n = 0; n < 2; ++n) {
                acc[m][n] = MFMA16(av[m][0], bv[n][0], acc[m][n]);
                acc[m][n] = MFMA16(av[m][1], bv[n][1], acc[m][n]);
            }
        __builtin_amdgcn_s_setprio(0);
        __builtin_amdgcn_s_barrier();

        // ---- phase 1: read B-high(4); stage next-tile B halves
#pragma unroll
        for (int n = 2; n < 4; ++n) {
            bv[n][0] = *(const bf16x8*)((const char*)lds + cb + aBbase + n * 2048 + sw0);
            bv[n][1] = *(const bf16x8*)((const char*)lds + cb + aBbase + n * 2048 + (sw0 ^ 64u));
        }
        if (st) { STAGE_B(nb, kt1, 0); STAGE_B(nb, kt1, 1); }
        __builtin_amdgcn_s_barrier();
        asm volatile("s_waitcnt lgkmcnt(0)" ::: "memory");
        __builtin_amdgcn_sched_barrier(0);
        __builtin_amdgcn_s_setprio(1);
#pragma unroll
        for (int m = 0; m < 4; ++m)
#pragma unroll
            for (int n = 2; n < 4; ++n) {
                acc[m][n] = MFMA16(av[m][0], bv[n][0], acc[m][n]);
                acc[m][n] = MFMA16(av[m][1], bv[n][1], acc[m][n]);
            }
        __builtin_amdgcn_s_setprio(0);
        __builtin_amdgcn_s_barrier();

        // ---- phase 2: read A-high(8)
#pragma unroll
        for (int m = 0; m < 4; ++m) {
            av[m][0] = *(const bf16x8*)((const char*)lds + cb + aAbase + (m + 4) * 2048 + sw0);
            av[m][1] = *(const bf16x8*)((const char*)lds + cb + aAbase + (m + 4) * 2048 + (sw0 ^ 64u));
        }
        __builtin_amdgcn_s_barrier();
        asm volatile("s_waitcnt lgkmcnt(0)" ::: "memory");
        __builtin_amdgcn_sched_barrier(0);
        __builtin_amdgcn_s_setprio(1);
#pragma unroll
        for (int m = 0; m < 4; ++m)
#pragma unroll
            for (int n = 0; n < 2; ++n) {
                acc[m + 4][n] = MFMA16(av[m][0], bv[n][0], acc[m + 4][n]);
                acc[m + 4][n] = MFMA16(av[m][1], bv[n][1], acc[m + 4][n]);
            }
        __builtin_amdgcn_s_setprio(0);
        __builtin_amdgcn_s_barrier();

        // ---- phase 3: pure MFMA (A-high x B-high)
        __builtin_amdgcn_s_setprio(1);
#pragma unroll
        for (int m = 0; m < 4; ++m)
#pragma unroll
            for (int n = 2; n < 4; ++n) {
                acc[m + 4][n] = MFMA16(av[m][0], bv[n][0], acc[m + 4][n]);
                acc[m + 4][n] = MFMA16(av[m][1], bv[n][1], acc[m + 4][n]);
            }
        __builtin_amdgcn_s_setprio(0);
    }

    // ---- epilogue: C row = (l>>4)*4 + j, col = l&15 within each 16x16 frag [m89]
    const int fr = l & 15, fq = (l >> 4) << 2;
    u16*   Cb = (u16*)Cv + sC * bz;
    float* Cf = (float*)Cv + sC * bz;
#pragma unroll
    for (int mf = 0; mf < 8; ++mf) {
        const int r = row0 + (wm << 7) + (mf << 4) + fq;
#pragma unroll
        for (int nf = 0; nf < 4; ++nf) {
            const int c = col0 + (wn << 6) + (nf << 4) + fr;
#pragma unroll
            for (int j = 0; j < 4; ++j) {
                float vv = acc[mf][nf][j];
                if (BIAS == 1) vv += bias[c];
                else if (BIAS == 2) vv += bias[r + j];
                if (OUT_BF16) Cb[(long long)(r + j) * ldc + c] = f2bf(vv);
                else          Cf[(long long)(r + j) * ldc + c] = vv;
            }
        }
    }
}

// ---------------------------------------------------------------- row softmax (bf16 in/out, in place)
__global__ __launch_bounds__(256, 4)
void softmax_kernel(u16* __restrict__ sc, float scale2) {
    u16* row = sc + (long long)blockIdx.x * NS;
    const int t = threadIdx.x;
    u16x8 a = ((const u16x8*)row)[t];
    float x[8];
#pragma unroll
    for (int j = 0; j < 8; ++j) x[j] = bf2f(a[j]);
    float m = x[0];
#pragma unroll
    for (int j = 1; j < 8; ++j) m = fmaxf(m, x[j]);
#pragma unroll
    for (int off = 1; off < 64; off <<= 1) m = fmaxf(m, __shfl_xor(m, off));
    __shared__ float red[2][4];
    const int w = t >> 6;
    if ((t & 63) == 0) red[0][w] = m;
    __syncthreads();
    m = fmaxf(fmaxf(red[0][0], red[0][1]), fmaxf(red[0][2], red[0][3]));
    float e[8], s = 0.f;
#pragma unroll
    for (int j = 0; j < 8; ++j) { e[j] = exp2f((x[j] - m) * scale2); s += e[j]; }
#pragma unroll
    for (int off = 1; off < 64; off <<= 1) s += __shfl_xor(s, off);
    if ((t & 63) == 0) red[1][w] = s;
    __syncthreads();
    s = red[1][0] + red[1][1] + red[1][2] + red[1][3];
    const float inv = 1.0f / s;
    u16x8 o;
#pragma unroll
    for (int j = 0; j < 8; ++j) o[j] = f2bf(e[j] * inv);
    ((u16x8*)row)[t] = o;
}

// ---------------------------------------------------------------- launch
extern "C" void kernel_launch(void* const* d_in, const int* in_sizes, int n_in,
                              void* d_out, int out_size, void* d_ws, size_t ws_size,
                              hipStream_t stream) {
    const float* q  = (const float*)d_in[0];
    const float* k  = (const float*)d_in[1];
    const float* v  = (const float*)d_in[2];
    const float* wq = (const float*)d_in[3];
    const float* bq = (const float*)d_in[4];
    const float* wk = (const float*)d_in[5];
    const float* bk = (const float*)d_in[6];
    const float* wv = (const float*)d_in[7];
    const float* bv = (const float*)d_in[8];
    float* out = (float*)d_out;

    char* ws = (char*)d_ws;
    const long long NIN = (long long)NB * NS * ND;     // 16,777,216 elems
    const long long NW  = (long long)ND * ND;          // 1,048,576 elems
    const long long NSC = (long long)NB * NS * NS;     // 33,554,432 elems

    // Workspace (160 MiB): [SCB bf16 scores 67MB | QB 33.5 | KB 33.5 | VT 33.5]
    // X (33.5MB) and W (2MB) alias the SCB region (dead before scores are written).
    u16* SCB = (u16*)ws;
    u16* X   = (u16*)ws;
    u16* W   = X + NIN;
    u16* QB  = SCB + NSC;
    u16* KB  = QB + NIN;
    u16* VT  = KB + NIN;
    (void)ws_size; (void)in_sizes; (void)n_in; (void)out_size;

    // 1) Q projection
    cvt_f32_bf16<<<16384, 256, 0, stream>>>(q,  X, (int)(NIN / 4));
    cvt_f32_bf16<<<1024,  256, 0, stream>>>(wq, W, (int)(NW / 4));
    gemm256_kernel<1, 1><<<dim3(4, 64, 1), 512, 0, stream>>>(
        X, 0, ND, W, 0, ND, QB, 0, ND, bq, ND);

    // 2) K projection
    cvt_f32_bf16<<<16384, 256, 0, stream>>>(k,  X, (int)(NIN / 4));
    cvt_f32_bf16<<<1024,  256, 0, stream>>>(wk, W, (int)(NW / 4));
    gemm256_kernel<1, 1><<<dim3(4, 64, 1), 512, 0, stream>>>(
        X, 0, ND, W, 0, ND, KB, 0, ND, bk, ND);

    // 3) V^T projection: VT[b][v][s] = sum_d Wv[v,d]*Xv[b,s,d] + bv[v]
    cvt_f32_bf16<<<16384, 256, 0, stream>>>(v,  X, (int)(NIN / 4));
    cvt_f32_bf16<<<1024,  256, 0, stream>>>(wv, W, (int)(NW / 4));
    gemm256_kernel<1, 2><<<dim3(8, 4, NB), 512, 0, stream>>>(
        W, 0, ND, X, (long long)NS * ND, ND, VT, (long long)ND * NS, NS, bv, ND);

    // 4) scores[b] = Q[b] * K[b]^T  (bf16 out; X/W dead, SCB overwrites them)
    gemm256_kernel<1, 0><<<dim3(8, 8, NB), 512, 0, stream>>>(
        QB, (long long)NS * ND, ND, KB, (long long)NS * ND, ND,
        SCB, (long long)NS * NS, NS, nullptr, ND);

    // 5) softmax rows (scale folded into exp2)
    const float scale2 = (1.0f / 32.0f) * 1.44269504088896f; // 1/sqrt(1024)*log2(e)
    softmax_kernel<<<NB * NS, 256, 0, stream>>>(SCB, scale2);

    // 6) out[b] = attn[b] * V[b] : A = bf16 attn, B^T = V^T[b], f32 out
    gemm256_kernel<0, 0><<<dim3(4, 8, NB), 512, 0, stream>>>(
        SCB, (long long)NS * NS, NS,
        VT, (long long)ND * NS, NS,
        out, (long long)NS * ND, ND, nullptr, NS);
}